// Round 8
// baseline (549.573 us; speedup 1.0000x reference)
//
#include <hip/hip_runtime.h>
#include <hip/hip_cooperative_groups.h>
#include <math.h>

namespace cg = cooperative_groups;

#define N_NODES 50000
#define N_REL   1000
#define D       128
#define NNZ     800000

#define G       64               // edge chunks
#define CHUNK   (NNZ / G)        // 12500 edges per chunk
#define P       8                // row ranges
#define RNG     (N_NODES / P)    // 6250 rows per range
#define NBLK    512              // grid blocks (== G*P)
#define NTHR    512              // threads per block (8 waves)
#define WPB     (NTHR / 64)      // 8 waves per block
#define SCAN_N  (N_NODES * G)    // 3,200,000 table entries
#define TILE    1024             // scan tile (entries)
#define NTILES  (SCAN_N / TILE)  // 3125 tiles

// ---------------- phase 0: per-relation exp(leaky_relu(score)); zero denom ----------
__device__ __forceinline__ void ph_scores(int bid, int tid,
        const float* __restrict__ dual, const float* __restrict__ conv_w,
        const float* __restrict__ conv_b, float* __restrict__ exp_scores,
        float* __restrict__ denom) {
    int wid = bid * WPB + (tid >> 6);       // one wave per relation
    int lane = tid & 63;
    if (wid < N_REL) {
        const float* row = dual + (long)wid * D;
        float s = row[lane] * conv_w[lane] + row[lane + 64] * conv_w[lane + 64];
        #pragma unroll
        for (int off = 32; off > 0; off >>= 1) s += __shfl_down(s, off);
        if (lane == 0) {
            float v = s + conv_b[0];
            v = (v >= 0.f) ? v : 0.01f * v;             // leaky_relu
            exp_scores[wid] = expf(v);                  // scores ~N(0,1): safe
        }
    }
    if (bid == 0 && tid == 0) *denom = 0.f;
}

// ------ phase 1: per-(chunk,range) LDS u16 histogram -> count table; fused denom -----
__device__ __forceinline__ void ph_phaseA(int bid, int tid,
        const int* __restrict__ rows, const int* __restrict__ rel,
        const float* __restrict__ exp_scores, unsigned* __restrict__ table,
        float* __restrict__ denom) {
    __shared__ unsigned hA[RNG / 2];        // 12.5 KB packed u16 counts
    __shared__ float wpart[WPB];
    int b = bid >> 3;                       // chunk 0..63
    int p = bid & 7;                        // range 0..7
    for (int i = tid; i < RNG / 2; i += NTHR) hA[i] = 0;
    __syncthreads();
    int cbase4 = b * (CHUNK / 4);
    int rlo = p * RNG;
    float dsum = 0.f;
    for (int j = tid; j < CHUNK / 4; j += NTHR) {
        int4 rr = ((const int4*)rows)[cbase4 + j];
        if (p == 0) {                       // denom: each edge counted once
            int4 rl = ((const int4*)rel)[cbase4 + j];
            dsum += exp_scores[rl.x] + exp_scores[rl.y]
                  + exp_scores[rl.z] + exp_scores[rl.w];
        }
        unsigned u;
        u = (unsigned)(rr.x - rlo); if (u < (unsigned)RNG) atomicAdd(&hA[u >> 1], 1u << ((u & 1) * 16));
        u = (unsigned)(rr.y - rlo); if (u < (unsigned)RNG) atomicAdd(&hA[u >> 1], 1u << ((u & 1) * 16));
        u = (unsigned)(rr.z - rlo); if (u < (unsigned)RNG) atomicAdd(&hA[u >> 1], 1u << ((u & 1) * 16));
        u = (unsigned)(rr.w - rlo); if (u < (unsigned)RNG) atomicAdd(&hA[u >> 1], 1u << ((u & 1) * 16));
    }
    if (p == 0) {                           // block-uniform branch: barrier safe
        #pragma unroll
        for (int off = 32; off > 0; off >>= 1) dsum += __shfl_down(dsum, off);
        if ((tid & 63) == 0) wpart[tid >> 6] = dsum;
        __syncthreads();
        if (tid == 0) {
            float v = 0.f;
            #pragma unroll
            for (int k = 0; k < WPB; ++k) v += wpart[k];
            atomicAdd(denom, v);            // 64 global atomics total
        }
    }
    __syncthreads();
    for (int i = tid; i < RNG; i += NTHR) {
        unsigned cnt = (hA[i >> 1] >> ((i & 1) * 16)) & 0xFFFFu;
        table[(unsigned)(rlo + i) * G + b] = cnt;
    }
}

// -------- phase 2a: tile-local exclusive scan over table; emit tile sums --------
__device__ __forceinline__ void ph_scanA(int bid, int tid,
        unsigned* __restrict__ table, unsigned* __restrict__ bsums) {
    __shared__ unsigned wsA[WPB];
    int lane = tid & 63, w = tid >> 6;
    for (int tile = bid; tile < NTILES; tile += NBLK) {
        uint2* a = (uint2*)(table + tile * TILE);
        uint2 x = a[tid];
        unsigned s2 = x.x + x.y;
        unsigned v = s2;
        #pragma unroll
        for (int off = 1; off < 64; off <<= 1) {
            unsigned y = __shfl_up(v, off);
            if (lane >= off) v += y;
        }
        if (lane == 63) wsA[w] = v;
        __syncthreads();
        if (tid == 0) {
            unsigned acc = 0;
            #pragma unroll
            for (int k = 0; k < WPB; ++k) { unsigned tmp = wsA[k]; wsA[k] = acc; acc += tmp; }
            bsums[tile] = acc;
        }
        __syncthreads();
        unsigned ex = wsA[w] + (v - s2);
        uint2 o; o.x = ex; o.y = ex + x.x;
        a[tid] = o;
        __syncthreads();                    // protect wsA before next tile
    }
}

// -------- phase 2b: exclusive scan of 3125 tile sums (block 0 only) --------
__device__ __forceinline__ void ph_scanB(int bid, int tid,
        unsigned* __restrict__ bsums, int* __restrict__ offsets) {
    if (bid != 0) return;
    __shared__ unsigned wsB[WPB];
    int lane = tid & 63, w = tid >> 6;
    unsigned vals[8];
    unsigned s = 0;
    #pragma unroll
    for (int k = 0; k < 8; ++k) {
        int idx = tid * 8 + k;              // 512*8 = 4096 >= 3125
        vals[k] = (idx < NTILES) ? bsums[idx] : 0;
        s += vals[k];
    }
    unsigned v = s;
    #pragma unroll
    for (int off = 1; off < 64; off <<= 1) {
        unsigned y = __shfl_up(v, off);
        if (lane >= off) v += y;
    }
    if (lane == 63) wsB[w] = v;
    __syncthreads();
    if (tid == 0) {
        unsigned acc = 0;
        #pragma unroll
        for (int k = 0; k < WPB; ++k) { unsigned tmp = wsB[k]; wsB[k] = acc; acc += tmp; }
    }
    __syncthreads();
    unsigned ex = wsB[w] + (v - s);
    #pragma unroll
    for (int k = 0; k < 8; ++k) {
        int idx = tid * 8 + k;
        if (idx < NTILES) bsums[idx] = ex;
        ex += vals[k];
    }
    if (tid == 0) offsets[N_NODES] = NNZ;
}

// -------- phase 2c: add tile prefix; emit per-row CSR offsets --------
__device__ __forceinline__ void ph_scanC(int bid, int tid,
        unsigned* __restrict__ table, const unsigned* __restrict__ bsums,
        int* __restrict__ offsets) {
    for (int tile = bid; tile < NTILES; tile += NBLK) {
        unsigned add = bsums[tile];
        uint2* a = (uint2*)(table + tile * TILE);
        uint2 x = a[tid];
        x.x += add; x.y += add;
        a[tid] = x;
        int g0 = tile * TILE + tid * 2;     // global table index (even)
        if ((g0 & (G - 1)) == 0) offsets[g0 >> 6] = (int)x.x;  // (r, b=0) -> row start
    }
}

// ------ phase 3: LDS cursors; place edges into bpack; weight on the fly ------
__device__ __forceinline__ void ph_phaseC(int bid, int tid,
        const int* __restrict__ rows, const int* __restrict__ cols,
        const int* __restrict__ rel, const float* __restrict__ exp_scores,
        const float* __restrict__ denom, const unsigned* __restrict__ table,
        int2* __restrict__ bpack) {
    __shared__ unsigned hC[RNG / 2];        // 12.5 KB packed u16 cursors
    int b = bid >> 3;
    int p = bid & 7;
    for (int i = tid; i < RNG / 2; i += NTHR) hC[i] = 0;
    __syncthreads();
    float inv = 1.0f / *denom;
    int cbase4 = b * (CHUNK / 4);
    int rlo = p * RNG;
    for (int j = tid; j < CHUNK / 4; j += NTHR) {
        int4 rr = ((const int4*)rows)[cbase4 + j];
        int4 cc = ((const int4*)cols)[cbase4 + j];
        int4 rl = ((const int4*)rel)[cbase4 + j];
        #pragma unroll
        for (int k = 0; k < 4; ++k) {
            int r = (k == 0) ? rr.x : (k == 1) ? rr.y : (k == 2) ? rr.z : rr.w;
            int c = (k == 0) ? cc.x : (k == 1) ? cc.y : (k == 2) ? cc.z : cc.w;
            int q = (k == 0) ? rl.x : (k == 1) ? rl.y : (k == 2) ? rl.z : rl.w;
            unsigned u = (unsigned)(r - rlo);
            if (u < (unsigned)RNG) {
                unsigned shift = (u & 1) * 16;
                unsigned old = atomicAdd(&hC[u >> 1], 1u << shift);
                unsigned lrank = (old >> shift) & 0xFFFFu;
                unsigned pos = table[(unsigned)r * G + b] + lrank;
                int2 pk; pk.x = c; pk.y = __float_as_int(exp_scores[q] * inv);
                bpack[pos] = pk;
            }
        }
    }
}

// ------ phase 4: gather — float4/lane, 2 rows per load, MLP=8, grid-stride ------
__device__ __forceinline__ void ph_gather(int bid, int tid,
        const int* __restrict__ offsets, const int2* __restrict__ bpack,
        const float* __restrict__ inlayer, float* __restrict__ out) {
    int wid = bid * WPB + (tid >> 6);
    int lane = tid & 63;
    int half = lane >> 5;
    int l32  = lane & 31;
    for (int node = wid; node < N_NODES; node += NBLK * WPB) {
        int s = offsets[node];
        int e = offsets[node + 1];
        float4 acc; acc.x = 0.f; acc.y = 0.f; acc.z = 0.f; acc.w = 0.f;
        for (int base = s; base < e; base += 64) {
            int rem = e - base; if (rem > 64) rem = 64;
            int px = 0, py = 0;
            if (lane < rem) {
                int2 p = bpack[base + lane];
                px = p.x; py = p.y;
            }
            for (int j = 0; j < rem; j += 8) {
                #pragma unroll
                for (int k = 0; k < 8; k += 2) {
                    int idx = j + k + half;
                    int   c = __shfl(px, idx);
                    float w = __int_as_float(__shfl(py, idx));
                    float4 v = ((const float4*)(inlayer + (long)c * D))[l32];
                    acc.x += w * v.x; acc.y += w * v.y;
                    acc.z += w * v.z; acc.w += w * v.w;
                }
            }
        }
        float4 tot;
        tot.x = acc.x + __shfl(acc.x, lane ^ 32);
        tot.y = acc.y + __shfl(acc.y, lane ^ 32);
        tot.z = acc.z + __shfl(acc.z, lane ^ 32);
        tot.w = acc.w + __shfl(acc.w, lane ^ 32);
        if (lane < 32)
            ((float4*)(out + (long)node * D))[l32] = tot;
    }
}

// =================== the cooperative mega-kernel (1 dispatch) ===================
__global__ void __launch_bounds__(NTHR, 4)
mega_kernel(const int* rows, const int* cols, const int* rel,
            const float* dual, const float* conv_w, const float* conv_b,
            const float* inlayer, float* out,
            float* exp_scores, float* denom, int* offsets,
            unsigned* table, unsigned* bsums, int2* bpack) {
    cg::grid_group grid = cg::this_grid();
    int bid = blockIdx.x, tid = threadIdx.x;
    ph_scores(bid, tid, dual, conv_w, conv_b, exp_scores, denom);
    grid.sync();
    ph_phaseA(bid, tid, rows, rel, exp_scores, table, denom);
    grid.sync();
    ph_scanA(bid, tid, table, bsums);
    grid.sync();
    ph_scanB(bid, tid, bsums, offsets);
    grid.sync();
    ph_scanC(bid, tid, table, bsums, offsets);
    grid.sync();
    ph_phaseC(bid, tid, rows, cols, rel, exp_scores, denom, table, bpack);
    grid.sync();
    ph_gather(bid, tid, offsets, bpack, inlayer, out);
}

// =================== fallback wrappers (non-cooperative path) ===================
__global__ void __launch_bounds__(NTHR) k_scores(const float* dual, const float* conv_w,
        const float* conv_b, float* exp_scores, float* denom) {
    ph_scores(blockIdx.x, threadIdx.x, dual, conv_w, conv_b, exp_scores, denom);
}
__global__ void __launch_bounds__(NTHR) k_phaseA(const int* rows, const int* rel,
        const float* exp_scores, unsigned* table, float* denom) {
    ph_phaseA(blockIdx.x, threadIdx.x, rows, rel, exp_scores, table, denom);
}
__global__ void __launch_bounds__(NTHR) k_scanA(unsigned* table, unsigned* bsums) {
    ph_scanA(blockIdx.x, threadIdx.x, table, bsums);
}
__global__ void __launch_bounds__(NTHR) k_scanB(unsigned* bsums, int* offsets) {
    ph_scanB(blockIdx.x, threadIdx.x, bsums, offsets);
}
__global__ void __launch_bounds__(NTHR) k_scanC(unsigned* table, const unsigned* bsums,
        int* offsets) {
    ph_scanC(blockIdx.x, threadIdx.x, table, bsums, offsets);
}
__global__ void __launch_bounds__(NTHR) k_phaseC(const int* rows, const int* cols,
        const int* rel, const float* exp_scores, const float* denom,
        const unsigned* table, int2* bpack) {
    ph_phaseC(blockIdx.x, threadIdx.x, rows, cols, rel, exp_scores, denom, table, bpack);
}
__global__ void __launch_bounds__(NTHR) k_gather(const int* offsets, const int2* bpack,
        const float* inlayer, float* out) {
    ph_gather(blockIdx.x, threadIdx.x, offsets, bpack, inlayer, out);
}

extern "C" void kernel_launch(void* const* d_in, const int* in_sizes, int n_in,
                              void* d_out, int out_size, void* d_ws, size_t ws_size,
                              hipStream_t stream) {
    const float* inlayer  = (const float*)d_in[0];
    const float* dual     = (const float*)d_in[1];
    const float* conv_w   = (const float*)d_in[2];
    const float* conv_b   = (const float*)d_in[3];
    const int*   edge_idx = (const int*)d_in[4];   // [2, NNZ]: rows then cols
    const int*   edge_rel = (const int*)d_in[5];
    float* out = (float*)d_out;
    const int* rows = edge_idx;
    const int* cols = edge_idx + NNZ;

    // workspace layout (16B aligned)
    char* ws = (char*)d_ws;
    float*    exp_scores = (float*)   (ws);                 // 1000 f
    float*    denom      = (float*)   (ws + 4096);          // 1 f
    int*      offsets    = (int*)     (ws + 8192);          // 50001 i
    unsigned* table      = (unsigned*)(ws + 212992);        // 3.2M u32 (12.8 MB)
    unsigned* bsums      = (unsigned*)(ws + 13012992);      // 3125 u32
    int2*     bpack      = (int2*)    (ws + 13029376);      // 800000 int2 (6.4 MB)

    void* args[] = {
        (void*)&rows, (void*)&cols, (void*)&edge_rel,
        (void*)&dual, (void*)&conv_w, (void*)&conv_b,
        (void*)&inlayer, (void*)&out,
        (void*)&exp_scores, (void*)&denom, (void*)&offsets,
        (void*)&table, (void*)&bsums, (void*)&bpack
    };
    hipError_t err = hipLaunchCooperativeKernel((void*)mega_kernel,
                                                dim3(NBLK), dim3(NTHR),
                                                args, 0, stream);
    if (err != hipSuccess) {
        // fallback: same phases as separate dispatches (R7-equivalent)
        k_scores<<<NBLK, NTHR, 0, stream>>>(dual, conv_w, conv_b, exp_scores, denom);
        k_phaseA<<<NBLK, NTHR, 0, stream>>>(rows, edge_rel, exp_scores, table, denom);
        k_scanA <<<NBLK, NTHR, 0, stream>>>(table, bsums);
        k_scanB <<<1,    NTHR, 0, stream>>>(bsums, offsets);
        k_scanC <<<NBLK, NTHR, 0, stream>>>(table, bsums, offsets);
        k_phaseC<<<NBLK, NTHR, 0, stream>>>(rows, cols, edge_rel, exp_scores,
                                            denom, table, bpack);
        k_gather<<<NBLK, NTHR, 0, stream>>>(offsets, bpack, inlayer, out);
    }
}

// Round 9
// 215.159 us; speedup vs baseline: 2.5543x; 2.5543x over previous
//
#include <hip/hip_runtime.h>
#include <math.h>

#define N_NODES 50000
#define N_REL   1000
#define D       128
#define NNZ     800000

#define G       64                 // edge chunks
#define CHUNK   (NNZ / G)          // 12500 edges per chunk
#define P       8                  // row ranges
#define RNG     (N_NODES / P)      // 6250 rows per range
#define NTHR    512                // threads for D1/D3
#define SCAN_N  (N_NODES * G)      // 3,200,000 table entries
#define TILE_E  8192               // scan tile entries
#define NTILES  ((SCAN_N + TILE_E - 1) / TILE_E)   // 391 tiles

// ============ D1: phaseA counting + fused scores + state zeroing ============
__global__ void __launch_bounds__(NTHR)
d1_kernel(const int* __restrict__ rows,
          const float* __restrict__ dual, const float* __restrict__ conv_w,
          const float* __restrict__ conv_b,
          float* __restrict__ exp_scores, unsigned* __restrict__ table,
          unsigned long long* __restrict__ state, unsigned* __restrict__ ticket,
          float* __restrict__ denom) {
    __shared__ unsigned hA[RNG / 2];       // 12.5 KB packed u16 counts
    int b = blockIdx.x;                    // chunk 0..63
    int p = blockIdx.y;                    // range 0..7
    int t = threadIdx.x;

    // ---- fused scores: p==0 blocks, one wave per relation (2 rounds) ----
    if (p == 0) {
        int wv = t >> 6, lane = t & 63;
        int wid = b * 8 + wv;              // 0..511
        #pragma unroll
        for (int rr = 0; rr < 2; ++rr) {
            int r = wid + rr * 512;
            if (r < N_REL) {
                const float* row = dual + (long)r * D;
                float s = row[lane] * conv_w[lane] + row[lane + 64] * conv_w[lane + 64];
                #pragma unroll
                for (int off = 32; off > 0; off >>= 1) s += __shfl_down(s, off);
                if (lane == 0) {
                    float v = s + conv_b[0];
                    v = (v >= 0.f) ? v : 0.01f * v;        // leaky_relu
                    exp_scores[r] = expf(v);               // ~N(0,1): safe
                }
            }
        }
    }
    // ---- zero lookback state / ticket / denom (block p==1,b==0) ----
    if (p == 1 && b == 0) {
        if (t < NTILES) state[t] = 0ULL;
        if (t == NTILES)     *ticket = 0u;
        if (t == NTILES + 1) *denom = 0.f;
    }

    // ---- LDS u16 histogram of this (chunk, range) ----
    for (int i = t; i < RNG / 2; i += NTHR) hA[i] = 0;
    __syncthreads();
    int cbase4 = b * (CHUNK / 4);
    int rlo = p * RNG;
    for (int j = t; j < CHUNK / 4; j += NTHR) {
        int4 rr = ((const int4*)rows)[cbase4 + j];
        unsigned u;
        u = (unsigned)(rr.x - rlo); if (u < (unsigned)RNG) atomicAdd(&hA[u >> 1], 1u << ((u & 1) * 16));
        u = (unsigned)(rr.y - rlo); if (u < (unsigned)RNG) atomicAdd(&hA[u >> 1], 1u << ((u & 1) * 16));
        u = (unsigned)(rr.z - rlo); if (u < (unsigned)RNG) atomicAdd(&hA[u >> 1], 1u << ((u & 1) * 16));
        u = (unsigned)(rr.w - rlo); if (u < (unsigned)RNG) atomicAdd(&hA[u >> 1], 1u << ((u & 1) * 16));
    }
    __syncthreads();
    for (int i = t; i < RNG; i += NTHR) {
        unsigned cnt = (hA[i >> 1] >> ((i & 1) * 16)) & 0xFFFFu;
        table[(unsigned)(rlo + i) * G + b] = cnt;
    }
}

// ============ D2: single-pass decoupled-lookback scan + denom ============
// 391 blocks x 256 threads; tile = 8192 entries (2048 uint4), register-stashed.
__global__ void __launch_bounds__(256)
d2_kernel(unsigned* __restrict__ table,
          unsigned long long* __restrict__ state, unsigned* __restrict__ ticket,
          const int* __restrict__ rel, const float* __restrict__ exp_scores,
          float* __restrict__ denom) {
    __shared__ unsigned wsum[4];
    __shared__ unsigned sh_total;
    __shared__ unsigned sh_base;
    __shared__ int sh_tile;
    __shared__ float fpart[4];
    int t = threadIdx.x;                   // 0..255
    int lane = t & 63, w = t >> 6;

    // ---- denom: grid-stride over edge relations ----
    float dsum = 0.f;
    for (int i = blockIdx.x * 256 + t; i < NNZ; i += gridDim.x * 256)
        dsum += exp_scores[rel[i]];
    #pragma unroll
    for (int off = 32; off > 0; off >>= 1) dsum += __shfl_down(dsum, off);
    if (lane == 0) fpart[w] = dsum;
    __syncthreads();
    if (t == 0)
        atomicAdd(denom, fpart[0] + fpart[1] + fpart[2] + fpart[3]);

    // ---- take ticket ----
    if (t == 0) sh_tile = (int)atomicAdd(ticket, 1u);
    __syncthreads();
    int tile = sh_tile;

    // ---- local scan of 8 sub-tiles (1024 entries each), stash in regs ----
    uint4 stash[8];
    unsigned carry = 0;
    int gbase = tile * (TILE_E / 4);       // uint4 index base
    #pragma unroll
    for (int k = 0; k < 8; ++k) {
        int gi = gbase + k * 256 + t;
        uint4 x;
        if (gi < SCAN_N / 4) x = ((const uint4*)table)[gi];
        else { x.x = 0; x.y = 0; x.z = 0; x.w = 0; }
        unsigned s4 = x.x + x.y + x.z + x.w;
        unsigned v = s4;
        #pragma unroll
        for (int off = 1; off < 64; off <<= 1) {
            unsigned y = __shfl_up(v, off);
            if (lane >= off) v += y;
        }
        if (lane == 63) wsum[w] = v;
        __syncthreads();
        if (t == 0) {
            unsigned acc = 0;
            #pragma unroll
            for (int q = 0; q < 4; ++q) { unsigned tmp = wsum[q]; wsum[q] = acc; acc += tmp; }
            sh_total = acc;
        }
        __syncthreads();
        unsigned ex = carry + wsum[w] + (v - s4);
        stash[k].x = ex;
        stash[k].y = ex + x.x;
        stash[k].z = ex + x.x + x.y;
        stash[k].w = ex + x.x + x.y + x.z;
        carry += sh_total;
        __syncthreads();                   // protect wsum/sh_total reuse
    }

    // ---- publish aggregate; lookback; publish inclusive ----
    if (t == 0) {
        atomicExch(&state[tile], (1ULL << 32) | (unsigned long long)carry);
        unsigned sum = 0;
        for (int pred = tile - 1; pred >= 0; --pred) {
            unsigned long long v;
            do { v = atomicAdd(&state[pred], 0ULL); } while ((v >> 32) == 0ULL);
            sum += (unsigned)v;
            if ((v >> 32) == 2ULL) break;
        }
        atomicExch(&state[tile], (2ULL << 32) | (unsigned long long)(sum + carry));
        sh_base = sum;
    }
    __syncthreads();
    unsigned base = sh_base;

    // ---- store final scanned values ----
    #pragma unroll
    for (int k = 0; k < 8; ++k) {
        int gi = gbase + k * 256 + t;
        if (gi < SCAN_N / 4) {
            uint4 o = stash[k];
            o.x += base; o.y += base; o.z += base; o.w += base;
            ((uint4*)table)[gi] = o;
        }
    }
}

// ============ D3: phaseC — LDS cursors, place edges, weight on the fly ============
__global__ void __launch_bounds__(NTHR)
d3_kernel(const int* __restrict__ rows, const int* __restrict__ cols,
          const int* __restrict__ rel, const float* __restrict__ exp_scores,
          const float* __restrict__ denom, const unsigned* __restrict__ table,
          int2* __restrict__ bpack) {
    __shared__ unsigned hC[RNG / 2];       // 12.5 KB packed u16 cursors
    int b = blockIdx.x;
    int p = blockIdx.y;
    int t = threadIdx.x;
    for (int i = t; i < RNG / 2; i += NTHR) hC[i] = 0;
    __syncthreads();
    float inv = 1.0f / *denom;
    int cbase4 = b * (CHUNK / 4);
    int rlo = p * RNG;
    for (int j = t; j < CHUNK / 4; j += NTHR) {
        int4 rr = ((const int4*)rows)[cbase4 + j];
        int4 cc = ((const int4*)cols)[cbase4 + j];
        int4 rl = ((const int4*)rel)[cbase4 + j];
        #pragma unroll
        for (int k = 0; k < 4; ++k) {
            int r = (k == 0) ? rr.x : (k == 1) ? rr.y : (k == 2) ? rr.z : rr.w;
            int c = (k == 0) ? cc.x : (k == 1) ? cc.y : (k == 2) ? cc.z : cc.w;
            int q = (k == 0) ? rl.x : (k == 1) ? rl.y : (k == 2) ? rl.z : rl.w;
            unsigned u = (unsigned)(r - rlo);
            if (u < (unsigned)RNG) {
                unsigned shift = (u & 1) * 16;
                unsigned old = atomicAdd(&hC[u >> 1], 1u << shift);
                unsigned lrank = (old >> shift) & 0xFFFFu;
                unsigned pos = table[(unsigned)r * G + b] + lrank;
                int2 pk; pk.x = c; pk.y = __float_as_int(exp_scores[q] * inv);
                bpack[pos] = pk;
            }
        }
    }
}

// ============ D4: gather — float4/lane, 2 rows per load, MLP=8 ============
__global__ void gather_kernel(const unsigned* __restrict__ table,
                              const int2* __restrict__ bpack,
                              const float* __restrict__ inlayer,
                              float* __restrict__ out) {
    int node = blockIdx.x * (blockDim.x >> 6) + (threadIdx.x >> 6);
    int lane = threadIdx.x & 63;
    if (node >= N_NODES) return;
    int s = (int)table[(unsigned)node << 6];             // row start = (node, chunk 0)
    int e = (node < N_NODES - 1) ? (int)table[(unsigned)(node + 1) << 6] : NNZ;
    int half = lane >> 5;
    int l32  = lane & 31;
    float4 acc; acc.x = 0.f; acc.y = 0.f; acc.z = 0.f; acc.w = 0.f;
    for (int base = s; base < e; base += 64) {
        int rem = e - base; if (rem > 64) rem = 64;
        int px = 0, py = 0;
        if (lane < rem) {
            int2 p = bpack[base + lane];
            px = p.x; py = p.y;
        }
        for (int j = 0; j < rem; j += 8) {
            #pragma unroll
            for (int k = 0; k < 8; k += 2) {
                int idx = j + k + half;
                int   c = __shfl(px, idx);
                float w = __int_as_float(__shfl(py, idx));
                float4 v = ((const float4*)(inlayer + (long)c * D))[l32];
                acc.x += w * v.x; acc.y += w * v.y;
                acc.z += w * v.z; acc.w += w * v.w;
            }
        }
    }
    float4 tot;
    tot.x = acc.x + __shfl(acc.x, lane ^ 32);
    tot.y = acc.y + __shfl(acc.y, lane ^ 32);
    tot.z = acc.z + __shfl(acc.z, lane ^ 32);
    tot.w = acc.w + __shfl(acc.w, lane ^ 32);
    if (lane < 32)
        ((float4*)(out + (long)node * D))[l32] = tot;
}

extern "C" void kernel_launch(void* const* d_in, const int* in_sizes, int n_in,
                              void* d_out, int out_size, void* d_ws, size_t ws_size,
                              hipStream_t stream) {
    const float* inlayer  = (const float*)d_in[0];
    const float* dual     = (const float*)d_in[1];
    const float* conv_w   = (const float*)d_in[2];
    const float* conv_b   = (const float*)d_in[3];
    const int*   edge_idx = (const int*)d_in[4];   // [2, NNZ]: rows then cols
    const int*   edge_rel = (const int*)d_in[5];
    float* out = (float*)d_out;
    const int* rows = edge_idx;
    const int* cols = edge_idx + NNZ;

    // workspace layout (16B aligned)
    char* ws = (char*)d_ws;
    float*              exp_scores = (float*)             (ws);              // 4 KB
    float*              denom      = (float*)             (ws + 4096);
    unsigned*           ticket     = (unsigned*)          (ws + 4160);
    unsigned long long* state      = (unsigned long long*)(ws + 8192);       // 391*8 B
    unsigned*           table      = (unsigned*)          (ws + 212992);     // 12.8 MB
    int2*               bpack      = (int2*)              (ws + 13029376);   // 6.4 MB

    d1_kernel<<<dim3(G, P), NTHR, 0, stream>>>(rows, dual, conv_w, conv_b,
                                               exp_scores, table, state, ticket, denom);
    d2_kernel<<<NTILES, 256, 0, stream>>>(table, state, ticket,
                                          edge_rel, exp_scores, denom);
    d3_kernel<<<dim3(G, P), NTHR, 0, stream>>>(rows, cols, edge_rel, exp_scores,
                                               denom, table, bpack);
    int grid = (N_NODES + 3) / 4;   // 4 waves/block, one node per wave
    gather_kernel<<<grid, 256, 0, stream>>>(table, bpack, inlayer, out);
}

// Round 10
// 187.788 us; speedup vs baseline: 2.9266x; 1.1458x over previous
//
#include <hip/hip_runtime.h>
#include <math.h>

#define N_NODES 50000
#define N_REL   1000
#define D       128
#define NNZ     800000

#define G       64                 // edge chunks
#define CHUNK   (NNZ / G)          // 12500 edges per chunk
#define P       8                  // row ranges
#define RNG     (N_NODES / P)      // 6250 rows per range
#define NTHR    512
#define TROWS   64                 // rows per scan tile
#define NTILES  ((N_NODES + TROWS - 1) / TROWS)   // 782

// ============ D1: per-(chunk,range) LDS histogram -> chunk-major table ============
// table[b*50000 + r] = count of edges with row r in chunk b  (coalesced writes)
// fused: relation scores (p==0 blocks), state/ticket/denom zeroing (p==1,b==0)
__global__ void __launch_bounds__(NTHR)
d1_kernel(const int* __restrict__ rows,
          const float* __restrict__ dual, const float* __restrict__ conv_w,
          const float* __restrict__ conv_b,
          float* __restrict__ exp_scores, unsigned* __restrict__ table,
          unsigned long long* __restrict__ state, unsigned* __restrict__ ticket,
          float* __restrict__ denom) {
    __shared__ unsigned hA[RNG / 2];       // 12.5 KB packed u16 counts
    int b = blockIdx.x;                    // chunk 0..63
    int p = blockIdx.y;                    // range 0..7
    int t = threadIdx.x;

    if (p == 0) {                          // fused scores: one wave per relation
        int wv = t >> 6, lane = t & 63;
        int wid = b * 8 + wv;              // 0..511
        #pragma unroll
        for (int rr = 0; rr < 2; ++rr) {
            int r = wid + rr * 512;
            if (r < N_REL) {
                const float* row = dual + (long)r * D;
                float s = row[lane] * conv_w[lane] + row[lane + 64] * conv_w[lane + 64];
                #pragma unroll
                for (int off = 32; off > 0; off >>= 1) s += __shfl_down(s, off);
                if (lane == 0) {
                    float v = s + conv_b[0];
                    v = (v >= 0.f) ? v : 0.01f * v;        // leaky_relu
                    exp_scores[r] = expf(v);               // ~N(0,1): safe
                }
            }
        }
    }
    if (p == 1 && b == 0) {                // zero scan state
        for (int i = t; i < NTILES; i += NTHR) state[i] = 0ULL;
        if (t == 0) { *ticket = 0u; *denom = 0.f; }
    }

    for (int i = t; i < RNG / 2; i += NTHR) hA[i] = 0;
    __syncthreads();
    int cbase4 = b * (CHUNK / 4);
    int rlo = p * RNG;
    for (int j = t; j < CHUNK / 4; j += NTHR) {
        int4 rr = ((const int4*)rows)[cbase4 + j];
        unsigned u;
        u = (unsigned)(rr.x - rlo); if (u < (unsigned)RNG) atomicAdd(&hA[u >> 1], 1u << ((u & 1) * 16));
        u = (unsigned)(rr.y - rlo); if (u < (unsigned)RNG) atomicAdd(&hA[u >> 1], 1u << ((u & 1) * 16));
        u = (unsigned)(rr.z - rlo); if (u < (unsigned)RNG) atomicAdd(&hA[u >> 1], 1u << ((u & 1) * 16));
        u = (unsigned)(rr.w - rlo); if (u < (unsigned)RNG) atomicAdd(&hA[u >> 1], 1u << ((u & 1) * 16));
    }
    __syncthreads();
    for (int i = t; i < RNG; i += NTHR) {  // coalesced chunk-major store
        unsigned cnt = (hA[i >> 1] >> ((i & 1) * 16)) & 0xFFFFu;
        table[(unsigned)b * N_NODES + (unsigned)(rlo + i)] = cnt;
    }
}

// ============ D2: row-major-order scan over chunk-major table ============
// logical tile = 64 rows x 64 chunks; LDS transpose; wave-parallel lookback.
// Result: table[b*50000+r] = global CSR start of segment (row r, chunk b).
// Also computes denom = sum_e exp_scores[rel_e].
__global__ void __launch_bounds__(256)
d2_kernel(unsigned* __restrict__ table,
          unsigned long long* __restrict__ state, unsigned* __restrict__ ticket,
          const int* __restrict__ rel, const float* __restrict__ exp_scores,
          float* __restrict__ denom) {
    __shared__ unsigned lds[TROWS * 65];   // padded transpose buffer (16.6 KB)
    __shared__ unsigned wsum[4];
    __shared__ unsigned sh_agg;
    __shared__ unsigned sh_base;
    __shared__ int sh_tile;
    __shared__ float fpart[4];
    int t = threadIdx.x;                   // 0..255
    int lane = t & 63, w = t >> 6;

    // ---- denom: grid-stride over edge relations ----
    float dsum = 0.f;
    for (int i = blockIdx.x * 256 + t; i < NNZ; i += gridDim.x * 256)
        dsum += exp_scores[rel[i]];
    #pragma unroll
    for (int off = 32; off > 0; off >>= 1) dsum += __shfl_down(dsum, off);
    if (lane == 0) fpart[w] = dsum;
    __syncthreads();
    if (t == 0)
        atomicAdd(denom, fpart[0] + fpart[1] + fpart[2] + fpart[3]);

    // ---- ticket: tiles processed in launch order of execution ----
    if (t == 0) sh_tile = (int)atomicAdd(ticket, 1u);
    __syncthreads();
    int tile = sh_tile;
    int r0 = tile * TROWS;
    bool full = (r0 + TROWS <= N_NODES);

    // ---- load tile: thread (b2 = t&63, q = t>>6) loads rows q*16..q*16+15 of slice b2
    int b2 = t & 63, q = t >> 6;
    #pragma unroll
    for (int k = 0; k < 4; ++k) {
        int j = q * 16 + k * 4;            // tile-local row
        if (full) {
            uint4 x = *(const uint4*)&table[(unsigned)b2 * N_NODES + (unsigned)(r0 + j)];
            lds[(j + 0) * 65 + b2] = x.x;
            lds[(j + 1) * 65 + b2] = x.y;
            lds[(j + 2) * 65 + b2] = x.z;
            lds[(j + 3) * 65 + b2] = x.w;
        } else {
            #pragma unroll
            for (int e = 0; e < 4; ++e) {
                int r = r0 + j + e;
                lds[(j + e) * 65 + b2] = (r < N_NODES)
                    ? table[(unsigned)b2 * N_NODES + (unsigned)r] : 0u;
            }
        }
    }
    __syncthreads();

    // ---- tile-local exclusive scan in row-major order (thread owns 16 cells) ----
    int j0 = t >> 2;                       // tile-local row of this thread's cells
    int c0 = (t & 3) * 16;                 // starting chunk
    unsigned vals[16];
    unsigned run = 0;
    #pragma unroll
    for (int k = 0; k < 16; ++k) {
        unsigned v = lds[j0 * 65 + c0 + k];
        vals[k] = run;
        run += v;
    }
    unsigned v = run;                      // wave inclusive scan of thread totals
    #pragma unroll
    for (int off = 1; off < 64; off <<= 1) {
        unsigned y = __shfl_up(v, off);
        if (lane >= off) v += y;
    }
    if (lane == 63) wsum[w] = v;
    __syncthreads();
    if (t == 0) {
        unsigned acc = 0;
        #pragma unroll
        for (int k = 0; k < 4; ++k) { unsigned tmp = wsum[k]; wsum[k] = acc; acc += tmp; }
        sh_agg = acc;                      // tile aggregate
    }
    __syncthreads();
    unsigned tbase = wsum[w] + (v - run);
    #pragma unroll
    for (int k = 0; k < 16; ++k)
        lds[j0 * 65 + c0 + k] = tbase + vals[k];

    // ---- publish aggregate; wave-parallel decoupled lookback ----
    if (t == 0)
        atomicExch(&state[tile], (1ULL << 32) | (unsigned long long)sh_agg);
    if (t < 64) {
        unsigned sum = 0;
        if (tile > 0) {
            int base_pred = tile - 1;
            for (;;) {
                int pred = base_pred - t;
                unsigned long long sv;
                if (pred >= 0) {
                    do { sv = atomicAdd(&state[pred], 0ULL); } while ((sv >> 32) == 0ULL);
                } else {
                    sv = (2ULL << 32);     // virtual predecessor: inclusive 0
                }
                unsigned long long m2 = __ballot((sv >> 32) == 2ULL);
                int l2 = (m2 != 0ULL) ? (__ffsll((long long)m2) - 1) : 64;
                unsigned contrib = ((int)t <= l2) ? (unsigned)sv : 0u;
                #pragma unroll
                for (int off = 32; off > 0; off >>= 1)
                    contrib += __shfl_down(contrib, off);
                sum += __shfl(contrib, 0);
                if (m2 != 0ULL) break;
                base_pred -= 64;
            }
        }
        if (t == 0) {
            sh_base = sum;
            atomicExch(&state[tile],
                       (2ULL << 32) | (unsigned long long)(sum + sh_agg));
        }
    }
    __syncthreads();
    unsigned gbase = sh_base;

    // ---- writeback transposed + global base (coalesced) ----
    #pragma unroll
    for (int k = 0; k < 4; ++k) {
        int j = q * 16 + k * 4;
        if (full) {
            uint4 o;
            o.x = lds[(j + 0) * 65 + b2] + gbase;
            o.y = lds[(j + 1) * 65 + b2] + gbase;
            o.z = lds[(j + 2) * 65 + b2] + gbase;
            o.w = lds[(j + 3) * 65 + b2] + gbase;
            *(uint4*)&table[(unsigned)b2 * N_NODES + (unsigned)(r0 + j)] = o;
        } else {
            #pragma unroll
            for (int e = 0; e < 4; ++e) {
                int r = r0 + j + e;
                if (r < N_NODES)
                    table[(unsigned)b2 * N_NODES + (unsigned)r] =
                        lds[(j + e) * 65 + b2] + gbase;
            }
        }
    }
}

// ============ D3: place edges — LDS segment starts + LDS cursors ============
__global__ void __launch_bounds__(NTHR)
d3_kernel(const int* __restrict__ rows, const int* __restrict__ cols,
          const int* __restrict__ rel, const float* __restrict__ exp_scores,
          const float* __restrict__ denom, const unsigned* __restrict__ table,
          int2* __restrict__ bpack) {
    __shared__ unsigned start[RNG];        // 25 KB: segment starts for this slice
    __shared__ unsigned cur[RNG / 2];      // 12.5 KB packed u16 cursors
    int b = blockIdx.x;
    int p = blockIdx.y;
    int t = threadIdx.x;
    int rlo = p * RNG;
    for (int i = t; i < RNG; i += NTHR)    // coalesced contiguous slice load
        start[i] = table[(unsigned)b * N_NODES + (unsigned)(rlo + i)];
    for (int i = t; i < RNG / 2; i += NTHR) cur[i] = 0;
    __syncthreads();
    float inv = 1.0f / *denom;
    int cbase4 = b * (CHUNK / 4);
    for (int j = t; j < CHUNK / 4; j += NTHR) {
        int4 rr = ((const int4*)rows)[cbase4 + j];
        int4 cc = ((const int4*)cols)[cbase4 + j];
        int4 rl = ((const int4*)rel)[cbase4 + j];
        #pragma unroll
        for (int k = 0; k < 4; ++k) {
            int r = (k == 0) ? rr.x : (k == 1) ? rr.y : (k == 2) ? rr.z : rr.w;
            int c = (k == 0) ? cc.x : (k == 1) ? cc.y : (k == 2) ? cc.z : cc.w;
            int q = (k == 0) ? rl.x : (k == 1) ? rl.y : (k == 2) ? rl.z : rl.w;
            unsigned u = (unsigned)(r - rlo);
            if (u < (unsigned)RNG) {
                unsigned shift = (u & 1) * 16;
                unsigned old = atomicAdd(&cur[u >> 1], 1u << shift);
                unsigned lrank = (old >> shift) & 0xFFFFu;
                unsigned pos = start[u] + lrank;
                int2 pk; pk.x = c; pk.y = __float_as_int(exp_scores[q] * inv);
                bpack[pos] = pk;
            }
        }
    }
}

// ============ D4: gather — float4/lane, 2 rows per load, MLP=8 ============
// row starts = chunk-0 slice of scanned table = table[0..50000) (contiguous)
__global__ void gather_kernel(const unsigned* __restrict__ table,
                              const int2* __restrict__ bpack,
                              const float* __restrict__ inlayer,
                              float* __restrict__ out) {
    int node = blockIdx.x * (blockDim.x >> 6) + (threadIdx.x >> 6);
    int lane = threadIdx.x & 63;
    if (node >= N_NODES) return;
    int s = (int)table[node];
    int e = (node < N_NODES - 1) ? (int)table[node + 1] : NNZ;
    int half = lane >> 5;
    int l32  = lane & 31;
    float4 acc; acc.x = 0.f; acc.y = 0.f; acc.z = 0.f; acc.w = 0.f;
    for (int base = s; base < e; base += 64) {
        int rem = e - base; if (rem > 64) rem = 64;
        int px = 0, py = 0;
        if (lane < rem) {
            int2 p = bpack[base + lane];
            px = p.x; py = p.y;
        }
        for (int j = 0; j < rem; j += 8) {
            #pragma unroll
            for (int k = 0; k < 8; k += 2) {
                int idx = j + k + half;
                int   c = __shfl(px, idx);
                float w = __int_as_float(__shfl(py, idx));
                float4 v = ((const float4*)(inlayer + (long)c * D))[l32];
                acc.x += w * v.x; acc.y += w * v.y;
                acc.z += w * v.z; acc.w += w * v.w;
            }
        }
    }
    float4 tot;
    tot.x = acc.x + __shfl(acc.x, lane ^ 32);
    tot.y = acc.y + __shfl(acc.y, lane ^ 32);
    tot.z = acc.z + __shfl(acc.z, lane ^ 32);
    tot.w = acc.w + __shfl(acc.w, lane ^ 32);
    if (lane < 32)
        ((float4*)(out + (long)node * D))[l32] = tot;
}

extern "C" void kernel_launch(void* const* d_in, const int* in_sizes, int n_in,
                              void* d_out, int out_size, void* d_ws, size_t ws_size,
                              hipStream_t stream) {
    const float* inlayer  = (const float*)d_in[0];
    const float* dual     = (const float*)d_in[1];
    const float* conv_w   = (const float*)d_in[2];
    const float* conv_b   = (const float*)d_in[3];
    const int*   edge_idx = (const int*)d_in[4];   // [2, NNZ]: rows then cols
    const int*   edge_rel = (const int*)d_in[5];
    float* out = (float*)d_out;
    const int* rows = edge_idx;
    const int* cols = edge_idx + NNZ;

    // workspace layout (16B aligned)
    char* ws = (char*)d_ws;
    float*              exp_scores = (float*)             (ws);             // 4 KB
    float*              denom      = (float*)             (ws + 4096);
    unsigned*           ticket     = (unsigned*)          (ws + 4160);
    unsigned long long* state      = (unsigned long long*)(ws + 8192);      // 782*8 B
    unsigned*           table      = (unsigned*)          (ws + 32768);     // 12.8 MB
    int2*               bpack      = (int2*)              (ws + 32768 + 12800000); // 6.4 MB

    d1_kernel<<<dim3(G, P), NTHR, 0, stream>>>(rows, dual, conv_w, conv_b,
                                               exp_scores, table, state, ticket, denom);
    d2_kernel<<<NTILES, 256, 0, stream>>>(table, state, ticket,
                                          edge_rel, exp_scores, denom);
    d3_kernel<<<dim3(G, P), NTHR, 0, stream>>>(rows, cols, edge_rel, exp_scores,
                                               denom, table, bpack);
    int grid = (N_NODES + 3) / 4;   // 4 waves/block, one node per wave
    gather_kernel<<<grid, 256, 0, stream>>>(table, bpack, inlayer, out);
}

// Round 11
// 176.833 us; speedup vs baseline: 3.1079x; 1.0619x over previous
//
#include <hip/hip_runtime.h>
#include <hip/hip_fp16.h>
#include <math.h>

#define N_NODES 50000
#define N_REL   1000
#define D       128
#define NNZ     800000

#define G       64                 // edge chunks
#define CHUNK   (NNZ / G)          // 12500 edges per chunk
#define P       8                  // row ranges
#define RNG     (N_NODES / P)      // 6250 rows per range
#define NTHR    512
#define TROWS   64                 // rows per scan tile
#define NTILES  ((N_NODES + TROWS - 1) / TROWS)   // 782

// ============ D1: LDS histogram -> chunk-major table; fused scores + f32->f16 ========
__global__ void __launch_bounds__(NTHR)
d1_kernel(const int* __restrict__ rows,
          const float* __restrict__ dual, const float* __restrict__ conv_w,
          const float* __restrict__ conv_b, const float* __restrict__ inlayer,
          float* __restrict__ exp_scores, unsigned* __restrict__ table,
          unsigned long long* __restrict__ state, unsigned* __restrict__ ticket,
          float* __restrict__ denom, __half2* __restrict__ hinl) {
    __shared__ unsigned hA[RNG / 2];       // 12.5 KB packed u16 counts
    int b = blockIdx.x;                    // chunk 0..63
    int p = blockIdx.y;                    // range 0..7
    int t = threadIdx.x;

    if (p == 0) {                          // fused scores: one wave per relation
        int wv = t >> 6, lane = t & 63;
        int wid = b * 8 + wv;              // 0..511
        #pragma unroll
        for (int rr = 0; rr < 2; ++rr) {
            int r = wid + rr * 512;
            if (r < N_REL) {
                const float* row = dual + (long)r * D;
                float s = row[lane] * conv_w[lane] + row[lane + 64] * conv_w[lane + 64];
                #pragma unroll
                for (int off = 32; off > 0; off >>= 1) s += __shfl_down(s, off);
                if (lane == 0) {
                    float v = s + conv_b[0];
                    v = (v >= 0.f) ? v : 0.01f * v;        // leaky_relu
                    exp_scores[r] = expf(v);               // ~N(0,1): safe
                }
            }
        }
    }
    if (p == 1 && b == 0) {                // zero scan state
        for (int i = t; i < NTILES; i += NTHR) state[i] = 0ULL;
        if (t == 0) { *ticket = 0u; *denom = 0.f; }
    }

    // fused: convert inlayer f32 -> f16 (grid-stride, coalesced)
    {
        int gtid = (p * G + b) * NTHR + t;                 // 0..262143
        const float2* src = (const float2*)inlayer;
        for (int i = gtid; i < N_NODES * D / 2; i += G * P * NTHR)
            hinl[i] = __float22half2_rn(src[i]);
    }

    for (int i = t; i < RNG / 2; i += NTHR) hA[i] = 0;
    __syncthreads();
    int cbase4 = b * (CHUNK / 4);
    int rlo = p * RNG;
    for (int j = t; j < CHUNK / 4; j += NTHR) {
        int4 rr = ((const int4*)rows)[cbase4 + j];
        unsigned u;
        u = (unsigned)(rr.x - rlo); if (u < (unsigned)RNG) atomicAdd(&hA[u >> 1], 1u << ((u & 1) * 16));
        u = (unsigned)(rr.y - rlo); if (u < (unsigned)RNG) atomicAdd(&hA[u >> 1], 1u << ((u & 1) * 16));
        u = (unsigned)(rr.z - rlo); if (u < (unsigned)RNG) atomicAdd(&hA[u >> 1], 1u << ((u & 1) * 16));
        u = (unsigned)(rr.w - rlo); if (u < (unsigned)RNG) atomicAdd(&hA[u >> 1], 1u << ((u & 1) * 16));
    }
    __syncthreads();
    for (int i = t; i < RNG; i += NTHR) {  // coalesced chunk-major store
        unsigned cnt = (hA[i >> 1] >> ((i & 1) * 16)) & 0xFFFFu;
        table[(unsigned)b * N_NODES + (unsigned)(rlo + i)] = cnt;
    }
}

// ============ D2: row-major-order scan over chunk-major table (+ denom) ============
__global__ void __launch_bounds__(256)
d2_kernel(unsigned* __restrict__ table,
          unsigned long long* __restrict__ state, unsigned* __restrict__ ticket,
          const int* __restrict__ rel, const float* __restrict__ exp_scores,
          float* __restrict__ denom) {
    __shared__ unsigned lds[TROWS * 65];   // padded transpose buffer (16.6 KB)
    __shared__ unsigned wsum[4];
    __shared__ unsigned sh_agg;
    __shared__ unsigned sh_base;
    __shared__ int sh_tile;
    __shared__ float fpart[4];
    int t = threadIdx.x;                   // 0..255
    int lane = t & 63, w = t >> 6;

    float dsum = 0.f;
    for (int i = blockIdx.x * 256 + t; i < NNZ; i += gridDim.x * 256)
        dsum += exp_scores[rel[i]];
    #pragma unroll
    for (int off = 32; off > 0; off >>= 1) dsum += __shfl_down(dsum, off);
    if (lane == 0) fpart[w] = dsum;
    __syncthreads();
    if (t == 0)
        atomicAdd(denom, fpart[0] + fpart[1] + fpart[2] + fpart[3]);

    if (t == 0) sh_tile = (int)atomicAdd(ticket, 1u);
    __syncthreads();
    int tile = sh_tile;
    int r0 = tile * TROWS;
    bool full = (r0 + TROWS <= N_NODES);

    int b2 = t & 63, q = t >> 6;
    #pragma unroll
    for (int k = 0; k < 4; ++k) {
        int j = q * 16 + k * 4;
        if (full) {
            uint4 x = *(const uint4*)&table[(unsigned)b2 * N_NODES + (unsigned)(r0 + j)];
            lds[(j + 0) * 65 + b2] = x.x;
            lds[(j + 1) * 65 + b2] = x.y;
            lds[(j + 2) * 65 + b2] = x.z;
            lds[(j + 3) * 65 + b2] = x.w;
        } else {
            #pragma unroll
            for (int e = 0; e < 4; ++e) {
                int r = r0 + j + e;
                lds[(j + e) * 65 + b2] = (r < N_NODES)
                    ? table[(unsigned)b2 * N_NODES + (unsigned)r] : 0u;
            }
        }
    }
    __syncthreads();

    int j0 = t >> 2;
    int c0 = (t & 3) * 16;
    unsigned vals[16];
    unsigned run = 0;
    #pragma unroll
    for (int k = 0; k < 16; ++k) {
        unsigned v = lds[j0 * 65 + c0 + k];
        vals[k] = run;
        run += v;
    }
    unsigned v = run;
    #pragma unroll
    for (int off = 1; off < 64; off <<= 1) {
        unsigned y = __shfl_up(v, off);
        if (lane >= off) v += y;
    }
    if (lane == 63) wsum[w] = v;
    __syncthreads();
    if (t == 0) {
        unsigned acc = 0;
        #pragma unroll
        for (int k = 0; k < 4; ++k) { unsigned tmp = wsum[k]; wsum[k] = acc; acc += tmp; }
        sh_agg = acc;
    }
    __syncthreads();
    unsigned tbase = wsum[w] + (v - run);
    #pragma unroll
    for (int k = 0; k < 16; ++k)
        lds[j0 * 65 + c0 + k] = tbase + vals[k];

    if (t == 0)
        atomicExch(&state[tile], (1ULL << 32) | (unsigned long long)sh_agg);
    if (t < 64) {
        unsigned sum = 0;
        if (tile > 0) {
            int base_pred = tile - 1;
            for (;;) {
                int pred = base_pred - t;
                unsigned long long sv;
                if (pred >= 0) {
                    do { sv = atomicAdd(&state[pred], 0ULL); } while ((sv >> 32) == 0ULL);
                } else {
                    sv = (2ULL << 32);
                }
                unsigned long long m2 = __ballot((sv >> 32) == 2ULL);
                int l2 = (m2 != 0ULL) ? (__ffsll((long long)m2) - 1) : 64;
                unsigned contrib = ((int)t <= l2) ? (unsigned)sv : 0u;
                #pragma unroll
                for (int off = 32; off > 0; off >>= 1)
                    contrib += __shfl_down(contrib, off);
                sum += __shfl(contrib, 0);
                if (m2 != 0ULL) break;
                base_pred -= 64;
            }
        }
        if (t == 0) {
            sh_base = sum;
            atomicExch(&state[tile],
                       (2ULL << 32) | (unsigned long long)(sum + sh_agg));
        }
    }
    __syncthreads();
    unsigned gbase = sh_base;

    #pragma unroll
    for (int k = 0; k < 4; ++k) {
        int j = q * 16 + k * 4;
        if (full) {
            uint4 o;
            o.x = lds[(j + 0) * 65 + b2] + gbase;
            o.y = lds[(j + 1) * 65 + b2] + gbase;
            o.z = lds[(j + 2) * 65 + b2] + gbase;
            o.w = lds[(j + 3) * 65 + b2] + gbase;
            *(uint4*)&table[(unsigned)b2 * N_NODES + (unsigned)(r0 + j)] = o;
        } else {
            #pragma unroll
            for (int e = 0; e < 4; ++e) {
                int r = r0 + j + e;
                if (r < N_NODES)
                    table[(unsigned)b2 * N_NODES + (unsigned)r] =
                        lds[(j + e) * 65 + b2] + gbase;
            }
        }
    }
}

// ============ D3: place edges — LDS segment starts + LDS cursors ============
__global__ void __launch_bounds__(NTHR)
d3_kernel(const int* __restrict__ rows, const int* __restrict__ cols,
          const int* __restrict__ rel, const float* __restrict__ exp_scores,
          const float* __restrict__ denom, const unsigned* __restrict__ table,
          int2* __restrict__ bpack) {
    __shared__ unsigned start[RNG];        // 25 KB
    __shared__ unsigned cur[RNG / 2];      // 12.5 KB packed u16 cursors
    int b = blockIdx.x;
    int p = blockIdx.y;
    int t = threadIdx.x;
    int rlo = p * RNG;
    for (int i = t; i < RNG; i += NTHR)
        start[i] = table[(unsigned)b * N_NODES + (unsigned)(rlo + i)];
    for (int i = t; i < RNG / 2; i += NTHR) cur[i] = 0;
    __syncthreads();
    float inv = 1.0f / *denom;
    int cbase4 = b * (CHUNK / 4);
    for (int j = t; j < CHUNK / 4; j += NTHR) {
        int4 rr = ((const int4*)rows)[cbase4 + j];
        int4 cc = ((const int4*)cols)[cbase4 + j];
        int4 rl = ((const int4*)rel)[cbase4 + j];
        #pragma unroll
        for (int k = 0; k < 4; ++k) {
            int r = (k == 0) ? rr.x : (k == 1) ? rr.y : (k == 2) ? rr.z : rr.w;
            int c = (k == 0) ? cc.x : (k == 1) ? cc.y : (k == 2) ? cc.z : cc.w;
            int q = (k == 0) ? rl.x : (k == 1) ? rl.y : (k == 2) ? rl.z : rl.w;
            unsigned u = (unsigned)(r - rlo);
            if (u < (unsigned)RNG) {
                unsigned shift = (u & 1) * 16;
                unsigned old = atomicAdd(&cur[u >> 1], 1u << shift);
                unsigned lrank = (old >> shift) & 0xFFFFu;
                unsigned pos = start[u] + lrank;
                int2 pk; pk.x = c; pk.y = __float_as_int(exp_scores[q] * inv);
                bpack[pos] = pk;
            }
        }
    }
}

// ============ D4: gather — fp16 rows, 16 lanes/row, 4 rows per load ============
__global__ void gather_kernel(const unsigned* __restrict__ table,
                              const int2* __restrict__ bpack,
                              const __half2* __restrict__ hinl,
                              float* __restrict__ out) {
    int node = blockIdx.x * (blockDim.x >> 6) + (threadIdx.x >> 6);
    int lane = threadIdx.x & 63;
    if (node >= N_NODES) return;
    int s = (int)table[node];
    int e = (node < N_NODES - 1) ? (int)table[node + 1] : NNZ;
    int quad = lane >> 4;                  // which of 4 rows per load
    int l16  = lane & 15;                  // 8-dim group within row
    float a0=0.f,a1=0.f,a2=0.f,a3=0.f,a4=0.f,a5=0.f,a6=0.f,a7=0.f;
    for (int base = s; base < e; base += 64) {
        int rem = e - base; if (rem > 64) rem = 64;
        int px = 0, py = 0;
        if (lane < rem) {
            int2 p = bpack[base + lane];   // coalesced 512B / 64 edges
            px = p.x; py = p.y;
        }
        for (int j = 0; j < rem; j += 16) {
            #pragma unroll
            for (int k = 0; k < 16; k += 4) {
                if (j + k < rem) {         // wave-uniform guard
                    int idx = j + k + quad;
                    int   c = __shfl(px, idx);           // 0 beyond rem -> w=0
                    float w = __int_as_float(__shfl(py, idx));
                    const __half2* hp = hinl + (long)c * (D / 2) + l16 * 4;
                    uint4 hv = *(const uint4*)hp;        // 8 halves (16B)
                    float2 f0 = __half22float2(*(const __half2*)&hv.x);
                    float2 f1 = __half22float2(*(const __half2*)&hv.y);
                    float2 f2 = __half22float2(*(const __half2*)&hv.z);
                    float2 f3 = __half22float2(*(const __half2*)&hv.w);
                    a0 += w * f0.x; a1 += w * f0.y;
                    a2 += w * f1.x; a3 += w * f1.y;
                    a4 += w * f2.x; a5 += w * f2.y;
                    a6 += w * f3.x; a7 += w * f3.y;
                }
            }
        }
    }
    // combine the 4 quads: butterfly over lane bits 4 and 5
    #define COMB(x) x += __shfl(x, lane ^ 16); x += __shfl(x, lane ^ 32);
    COMB(a0) COMB(a1) COMB(a2) COMB(a3) COMB(a4) COMB(a5) COMB(a6) COMB(a7)
    #undef COMB
    if (lane < 32) {                       // 32 lanes cover the 512B row store
        float4 v;
        int hi = (lane >> 4) & 1;          // 0: dims 0-3 of group, 1: dims 4-7
        if (hi) { v.x = a4; v.y = a5; v.z = a6; v.w = a7; }
        else    { v.x = a0; v.y = a1; v.z = a2; v.w = a3; }
        *(float4*)(out + (long)node * D + l16 * 8 + hi * 4) = v;
    }
}

extern "C" void kernel_launch(void* const* d_in, const int* in_sizes, int n_in,
                              void* d_out, int out_size, void* d_ws, size_t ws_size,
                              hipStream_t stream) {
    const float* inlayer  = (const float*)d_in[0];
    const float* dual     = (const float*)d_in[1];
    const float* conv_w   = (const float*)d_in[2];
    const float* conv_b   = (const float*)d_in[3];
    const int*   edge_idx = (const int*)d_in[4];   // [2, NNZ]: rows then cols
    const int*   edge_rel = (const int*)d_in[5];
    float* out = (float*)d_out;
    const int* rows = edge_idx;
    const int* cols = edge_idx + NNZ;

    // workspace layout (16B aligned) — total ~30.6 MB
    char* ws = (char*)d_ws;
    float*              exp_scores = (float*)             (ws);             // 4 KB
    float*              denom      = (float*)             (ws + 4096);
    unsigned*           ticket     = (unsigned*)          (ws + 4160);
    unsigned long long* state      = (unsigned long long*)(ws + 8192);      // 782*8 B
    unsigned*           table      = (unsigned*)          (ws + 32768);     // 12.8 MB
    int2*               bpack      = (int2*)              (ws + 32768 + 12800000);      // 6.4 MB
    __half2*            hinl       = (__half2*)           (ws + 32768 + 12800000 + 6400000); // 12.8 MB

    d1_kernel<<<dim3(G, P), NTHR, 0, stream>>>(rows, dual, conv_w, conv_b, inlayer,
                                               exp_scores, table, state, ticket,
                                               denom, hinl);
    d2_kernel<<<NTILES, 256, 0, stream>>>(table, state, ticket,
                                          edge_rel, exp_scores, denom);
    d3_kernel<<<dim3(G, P), NTHR, 0, stream>>>(rows, cols, edge_rel, exp_scores,
                                               denom, table, bpack);
    int grid = (N_NODES + 3) / 4;   // 4 waves/block, one node per wave
    gather_kernel<<<grid, 256, 0, stream>>>(table, bpack, hinl, out);
}